// Round 1
// baseline (942.728 us; speedup 1.0000x reference)
//
#include <hip/hip_runtime.h>
#include <stdint.h>

#define D_DIM 4096
#define O_DIM 4096
#define M_DIM 8192
#define SCALE_F 2.0f

typedef __attribute__((ext_vector_type(4))) float f32x4;
typedef __attribute__((ext_vector_type(8))) __bf16 bf16x8;
typedef __attribute__((ext_vector_type(8))) unsigned short u16x8;

__device__ __forceinline__ unsigned short f32_to_bf16_bits(float f) {
    union { float f; uint32_t u; } v; v.f = f;
    return (unsigned short)((v.u + 0x7FFFu + ((v.u >> 16) & 1u)) >> 16);
}

__device__ __forceinline__ float dot4(f32x4 a, f32x4 b) {
    return fmaf(a.x, b.x, fmaf(a.y, b.y, fmaf(a.z, b.z, a.w * b.w)));
}

// ---------------- Kernel 1: f32 -> bf16 convert (vectorized, grid-stride) ----------------
__global__ __launch_bounds__(256) void convert_bf16_kernel(const float* __restrict__ src,
                                                           unsigned short* __restrict__ dst,
                                                           int n4) {
    int stride = gridDim.x * blockDim.x;
    for (int i = blockIdx.x * blockDim.x + threadIdx.x; i < n4; i += stride) {
        f32x4 v = ((const f32x4*)src)[i];
        ushort4 o;
        o.x = f32_to_bf16_bits(v.x);
        o.y = f32_to_bf16_bits(v.y);
        o.z = f32_to_bf16_bits(v.z);
        o.w = f32_to_bf16_bits(v.w);
        ((ushort4*)dst)[i] = o;
    }
}

// ---------------- Kernel 2: mixed[m,16] = (softmax(x@router^T) weighted cores) applied to x@A^T --
// Block: 64 threads, 32 tokens. Skinny GEMM Y[32,24] = x_tile @ [A_w;router_w]^T with
// LDS-staged d-chunks and 4-token x 3-out register tiles, then softmax + core mixing.
__global__ __launch_bounds__(64) void mixed_kernel(const float* __restrict__ x,
                                                   const float* __restrict__ A_w,
                                                   const float* __restrict__ router_w,
                                                   const float* __restrict__ cores,
                                                   float* __restrict__ mixbuf) {
    __shared__ __align__(16) float Xc[32][128];   // 16 KiB
    __shared__ __align__(16) float Wc[24][128];   // 12 KiB
    __shared__ __align__(16) float Cs[2048];      // 8 KiB  cores[e][r][q]
    __shared__ float Ys[32][24];                  // 3 KiB

    const int tid = threadIdx.x;
    const int t0 = blockIdx.x * 32;

    // stage cores once (512 float4 / 64 threads = 8 each)
    #pragma unroll
    for (int i = 0; i < 8; ++i) {
        int idx = i * 64 + tid;
        ((f32x4*)Cs)[idx] = ((const f32x4*)cores)[idx];
    }

    const int tg = tid >> 3;  // 0..7 -> tokens tg*4..tg*4+3
    const int og = tid & 7;   // 0..7 -> outs og*3..og*3+2
    float acc[4][3];
    #pragma unroll
    for (int ti = 0; ti < 4; ++ti)
        #pragma unroll
        for (int wi = 0; wi < 3; ++wi) acc[ti][wi] = 0.f;

    for (int c = 0; c < 32; ++c) {  // 4096 / 128
        const int d0 = c * 128;
        __syncthreads();
        // stage Xc: 32x128 f32 = 1024 float4, 16 per thread
        #pragma unroll
        for (int i = 0; i < 16; ++i) {
            int idx = i * 64 + tid;
            int t = idx >> 5, dq = idx & 31;
            *(f32x4*)&Xc[t][dq * 4] =
                *(const f32x4*)&x[(size_t)(t0 + t) * D_DIM + d0 + dq * 4];
        }
        // stage Wc: 24x128 f32 = 768 float4, 12 per thread (rows 0..15 = A_w, 16..23 = router_w)
        #pragma unroll
        for (int i = 0; i < 12; ++i) {
            int idx = i * 64 + tid;
            int r = idx >> 5, dq = idx & 31;
            const float* src = (r < 16) ? (A_w + (size_t)r * D_DIM)
                                        : (router_w + (size_t)(r - 16) * D_DIM);
            *(f32x4*)&Wc[r][dq * 4] = *(const f32x4*)&src[d0 + dq * 4];
        }
        __syncthreads();
        for (int dq = 0; dq < 32; ++dq) {
            f32x4 w0 = *(const f32x4*)&Wc[og * 3 + 0][dq * 4];
            f32x4 w1 = *(const f32x4*)&Wc[og * 3 + 1][dq * 4];
            f32x4 w2 = *(const f32x4*)&Wc[og * 3 + 2][dq * 4];
            #pragma unroll
            for (int ti = 0; ti < 4; ++ti) {
                f32x4 xv = *(const f32x4*)&Xc[tg * 4 + ti][dq * 4];
                acc[ti][0] += dot4(xv, w0);
                acc[ti][1] += dot4(xv, w1);
                acc[ti][2] += dot4(xv, w2);
            }
        }
    }
    #pragma unroll
    for (int ti = 0; ti < 4; ++ti)
        #pragma unroll
        for (int wi = 0; wi < 3; ++wi) Ys[tg * 4 + ti][og * 3 + wi] = acc[ti][wi];
    __syncthreads();

    // phase 2: softmax over 8 logits + expert-core mixing; one thread per token
    if (tid < 32) {
        float ax[16];
        #pragma unroll
        for (int r = 0; r < 16; ++r) ax[r] = Ys[tid][r];
        float lg[8];
        #pragma unroll
        for (int e = 0; e < 8; ++e) lg[e] = Ys[tid][16 + e];
        float mx = lg[0];
        #pragma unroll
        for (int e = 1; e < 8; ++e) mx = fmaxf(mx, lg[e]);
        float p[8], psum = 0.f;
        #pragma unroll
        for (int e = 0; e < 8; ++e) { p[e] = __expf(lg[e] - mx); psum += p[e]; }
        const float inv = 1.0f / psum;
        float outq[16];
        #pragma unroll
        for (int q = 0; q < 16; ++q) outq[q] = 0.f;
        for (int e = 0; e < 8; ++e) {
            const float pe = p[e] * inv;
            #pragma unroll
            for (int r = 0; r < 16; ++r) {
                const float ar = ax[r] * pe;
                #pragma unroll
                for (int q = 0; q < 16; ++q)
                    outq[q] = fmaf(ar, Cs[(e * 16 + r) * 16 + q], outq[q]);
            }
        }
        const int tok = t0 + tid;
        #pragma unroll
        for (int q = 0; q < 4; ++q) {
            f32x4 v = {outq[q * 4 + 0], outq[q * 4 + 1], outq[q * 4 + 2], outq[q * 4 + 3]};
            *(f32x4*)&mixbuf[(size_t)tok * 16 + q * 4] = v;
        }
    }
}

// ---------------- Kernel 3: main GEMM (m97 structure) + fused LoRA/bias epilogue ----------
// C[m,o] = sum_d xbf[m,d]*wbf[o,d] + b[o] + 2.0 * sum_r mixed[m,r]*B_w[o,r]
// 128x128 tile, BK=32, 4 waves (2x2), mfma_f32_16x16x32_bf16, global_load_lds width=16.
__global__ __launch_bounds__(256) void gemm_kernel(const unsigned short* __restrict__ xbf,
                                                   const unsigned short* __restrict__ wbf,
                                                   const float* __restrict__ bias,
                                                   const float* __restrict__ Bw,
                                                   const float* __restrict__ mixbuf,
                                                   float* __restrict__ out) {
    __shared__ __align__(16) unsigned short As[128 * 32];  // 8 KiB
    __shared__ __align__(16) unsigned short Bs[128 * 32];  // 8 KiB

    // XCD-bijective swizzle: 2048 blocks % 8 == 0
    const int bid = blockIdx.x;
    const int lid = (bid & 7) * 256 + (bid >> 3);
    const int tm = lid & 63;   // 64 M-tiles
    const int tn = lid >> 6;   // 32 N-tiles
    const int m0 = tm * 128, n0 = tn * 128;

    const int tid = threadIdx.x;
    const int wave = tid >> 6, lane = tid & 63;
    const int wr = wave >> 1, wc = wave & 1;  // 2x2 wave grid, 64x64 per wave

    f32x4 acc[4][4];
    const f32x4 fz = {0.f, 0.f, 0.f, 0.f};
    #pragma unroll
    for (int mi = 0; mi < 4; ++mi)
        #pragma unroll
        for (int ni = 0; ni < 4; ++ni) acc[mi][ni] = fz;

    const int tA = lane & 15, kq = lane >> 4;

    for (int k0 = 0; k0 < D_DIM; k0 += 32) {
        // stage: A tile 128x32 bf16 = 512 16B-chunks; wave-uniform LDS base + lane*16
        #pragma unroll
        for (int i = 0; i < 2; ++i) {
            const int chunk = i * 256 + wave * 64 + lane;
            const int row = chunk >> 2;
            const int c8 = (chunk & 3) << 3;
            const unsigned short* ga = xbf + (size_t)(m0 + row) * D_DIM + k0 + c8;
            const unsigned short* gb = wbf + (size_t)(n0 + row) * D_DIM + k0 + c8;
            __builtin_amdgcn_global_load_lds(
                (const __attribute__((address_space(1))) void*)ga,
                (__attribute__((address_space(3))) void*)(As + (i * 256 + wave * 64) * 8),
                16, 0, 0);
            __builtin_amdgcn_global_load_lds(
                (const __attribute__((address_space(1))) void*)gb,
                (__attribute__((address_space(3))) void*)(Bs + (i * 256 + wave * 64) * 8),
                16, 0, 0);
        }
        __syncthreads();  // compiler drains vmcnt before barrier

        bf16x8 a[4], b[4];
        #pragma unroll
        for (int mi = 0; mi < 4; ++mi)
            a[mi] = __builtin_bit_cast(
                bf16x8, *(const u16x8*)&As[(wr * 64 + mi * 16 + tA) * 32 + kq * 8]);
        #pragma unroll
        for (int ni = 0; ni < 4; ++ni)
            b[ni] = __builtin_bit_cast(
                bf16x8, *(const u16x8*)&Bs[(wc * 64 + ni * 16 + tA) * 32 + kq * 8]);
        #pragma unroll
        for (int mi = 0; mi < 4; ++mi)
            #pragma unroll
            for (int ni = 0; ni < 4; ++ni)
                acc[mi][ni] =
                    __builtin_amdgcn_mfma_f32_16x16x32_bf16(a[mi], b[ni], acc[mi][ni], 0, 0, 0);
        __syncthreads();
    }

    // epilogue: C/D layout col=lane&15, row=(lane>>4)*4+j
    const int colq = lane & 15, rq = lane >> 4;
    f32x4 bwv[4][4];
    float bcol[4];
    #pragma unroll
    for (int ni = 0; ni < 4; ++ni) {
        const int col = n0 + wc * 64 + ni * 16 + colq;
        bcol[ni] = bias[col];
        #pragma unroll
        for (int k = 0; k < 4; ++k) bwv[ni][k] = *(const f32x4*)&Bw[(size_t)col * 16 + k * 4];
    }
    #pragma unroll
    for (int mi = 0; mi < 4; ++mi) {
        #pragma unroll
        for (int j = 0; j < 4; ++j) {
            const int row = m0 + wr * 64 + mi * 16 + rq * 4 + j;
            const f32x4* mx = (const f32x4*)&mixbuf[(size_t)row * 16];
            const f32x4 m0v = mx[0], m1v = mx[1], m2v = mx[2], m3v = mx[3];
            #pragma unroll
            for (int ni = 0; ni < 4; ++ni) {
                const int col = n0 + wc * 64 + ni * 16 + colq;
                const float lora = dot4(m0v, bwv[ni][0]) + dot4(m1v, bwv[ni][1]) +
                                   dot4(m2v, bwv[ni][2]) + dot4(m3v, bwv[ni][3]);
                out[(size_t)row * O_DIM + col] = acc[mi][ni][j] + bcol[ni] + SCALE_F * lora;
            }
        }
    }
}

extern "C" void kernel_launch(void* const* d_in, const int* in_sizes, int n_in,
                              void* d_out, int out_size, void* d_ws, size_t ws_size,
                              hipStream_t stream) {
    const float* x        = (const float*)d_in[0];
    const float* W_base   = (const float*)d_in[1];
    const float* b_base   = (const float*)d_in[2];
    const float* A_w      = (const float*)d_in[3];
    const float* B_w      = (const float*)d_in[4];
    const float* router_w = (const float*)d_in[5];
    const float* cores    = (const float*)d_in[6];
    float* out = (float*)d_out;

    char* ws = (char*)d_ws;
    unsigned short* xbf = (unsigned short*)ws;                                   // 64 MiB
    unsigned short* wbf = (unsigned short*)(ws + (size_t)M_DIM * D_DIM * 2);     // 32 MiB
    float* mixbuf = (float*)(ws + (size_t)M_DIM * D_DIM * 2 + (size_t)O_DIM * D_DIM * 2);  // 512 KiB

    convert_bf16_kernel<<<2048, 256, 0, stream>>>(x, xbf, (M_DIM * D_DIM) / 4);
    convert_bf16_kernel<<<2048, 256, 0, stream>>>(W_base, wbf, (O_DIM * D_DIM) / 4);
    mixed_kernel<<<M_DIM / 32, 64, 0, stream>>>(x, A_w, router_w, cores, mixbuf);
    gemm_kernel<<<2048, 256, 0, stream>>>(xbf, wbf, b_base, B_w, mixbuf, out);
}

// Round 2
// 598.655 us; speedup vs baseline: 1.5747x; 1.5747x over previous
//
#include <hip/hip_runtime.h>
#include <stdint.h>

#define D_DIM 4096
#define O_DIM 4096
#define M_DIM 8192
#define SCALE_F 2.0f

typedef __attribute__((ext_vector_type(4))) float f32x4;
typedef __attribute__((ext_vector_type(8))) __bf16 bf16x8;
typedef __attribute__((ext_vector_type(8))) unsigned short u16x8;

__device__ __forceinline__ unsigned short f32_to_bf16_bits(float f) {
    union { float f; uint32_t u; } v; v.f = f;
    return (unsigned short)((v.u + 0x7FFFu + ((v.u >> 16) & 1u)) >> 16);
}

__device__ __forceinline__ float dot4(f32x4 a, f32x4 b) {
    return fmaf(a.x, b.x, fmaf(a.y, b.y, fmaf(a.z, b.z, a.w * b.w)));
}

// ---------------- Kernel 1: f32 -> bf16 convert (vectorized, grid-stride) ----------------
__global__ __launch_bounds__(256) void convert_bf16_kernel(const float* __restrict__ src,
                                                           unsigned short* __restrict__ dst,
                                                           int n4) {
    int stride = gridDim.x * blockDim.x;
    for (int i = blockIdx.x * blockDim.x + threadIdx.x; i < n4; i += stride) {
        f32x4 v = ((const f32x4*)src)[i];
        ushort4 o;
        o.x = f32_to_bf16_bits(v.x);
        o.y = f32_to_bf16_bits(v.y);
        o.z = f32_to_bf16_bits(v.z);
        o.w = f32_to_bf16_bits(v.w);
        ((ushort4*)dst)[i] = o;
    }
}

// ---------------- Kernel 2a: partial Y[32,24] = x_tile @ [A_w;router_w]^T over a D-split ---
// grid (256 token-tiles, 8 D-splits), 256 threads. Each block covers 32 tokens x 512 d.
// LDS rows padded +4 floats (132) so row-stride = 4 banks -> conflict-free compute reads.
__global__ __launch_bounds__(256) void partial_mixed_kernel(const float* __restrict__ x,
                                                            const float* __restrict__ A_w,
                                                            const float* __restrict__ router_w,
                                                            float* __restrict__ ypart) {
    __shared__ __align__(16) float Xc[32][132];   // ~16.5 KiB
    __shared__ __align__(16) float Wc[24][132];   // ~12.4 KiB

    const int tid = threadIdx.x;
    const int t0 = blockIdx.x * 32;
    const int d0 = blockIdx.y * 512;

    const int tg = tid >> 3;  // token 0..31
    const int og = tid & 7;   // out group: cols og*3..og*3+2
    float acc0 = 0.f, acc1 = 0.f, acc2 = 0.f;

    for (int sub = 0; sub < 4; ++sub) {
        const int dbase = d0 + sub * 128;
        __syncthreads();
        // stage Xc: 32x128 f32 = 1024 float4, 4 per thread
        #pragma unroll
        for (int i = 0; i < 4; ++i) {
            int idx = i * 256 + tid;
            int t = idx >> 5, dq = idx & 31;
            *(f32x4*)&Xc[t][dq * 4] =
                *(const f32x4*)&x[(size_t)(t0 + t) * D_DIM + dbase + dq * 4];
        }
        // stage Wc: 24x128 f32 = 768 float4, 3 per thread
        #pragma unroll
        for (int i = 0; i < 3; ++i) {
            int idx = i * 256 + tid;
            int r = idx >> 5, dq = idx & 31;
            const float* src = (r < 16) ? (A_w + (size_t)r * D_DIM)
                                        : (router_w + (size_t)(r - 16) * D_DIM);
            *(f32x4*)&Wc[r][dq * 4] = *(const f32x4*)&src[dbase + dq * 4];
        }
        __syncthreads();
        #pragma unroll
        for (int dq = 0; dq < 32; ++dq) {
            f32x4 xv = *(const f32x4*)&Xc[tg][dq * 4];
            acc0 += dot4(xv, *(const f32x4*)&Wc[og * 3 + 0][dq * 4]);
            acc1 += dot4(xv, *(const f32x4*)&Wc[og * 3 + 1][dq * 4]);
            acc2 += dot4(xv, *(const f32x4*)&Wc[og * 3 + 2][dq * 4]);
        }
    }
    // ypart[ds][tile][t][24]
    float* dst = ypart + (((size_t)blockIdx.y * 256 + blockIdx.x) * 32 + tg) * 24 + og * 3;
    dst[0] = acc0; dst[1] = acc1; dst[2] = acc2;
}

// ---------------- Kernel 2b: finalize — reduce partials, softmax, expert-core mix ---------
// grid 64 x 128 threads, one thread per token.
__global__ __launch_bounds__(128) void finalize_mixed_kernel(const float* __restrict__ ypart,
                                                             const float* __restrict__ cores,
                                                             float* __restrict__ mixbuf) {
    __shared__ __align__(16) float Cs[2048];  // cores[e][r][q], 8 KiB
    const int tid = threadIdx.x;
    #pragma unroll
    for (int i = 0; i < 4; ++i) {
        int idx = i * 128 + tid;
        ((f32x4*)Cs)[idx] = ((const f32x4*)cores)[idx];
    }
    __syncthreads();

    const int tok = blockIdx.x * 128 + tid;
    const int tile = tok >> 5, t = tok & 31;

    float y[24];
    #pragma unroll
    for (int j = 0; j < 24; ++j) y[j] = 0.f;
    for (int ds = 0; ds < 8; ++ds) {
        const float* src = ypart + (((size_t)ds * 256 + tile) * 32 + t) * 24;
        #pragma unroll
        for (int j = 0; j < 24; ++j) y[j] += src[j];
    }

    float mx = y[16];
    #pragma unroll
    for (int e = 1; e < 8; ++e) mx = fmaxf(mx, y[16 + e]);
    float p[8], psum = 0.f;
    #pragma unroll
    for (int e = 0; e < 8; ++e) { p[e] = __expf(y[16 + e] - mx); psum += p[e]; }
    const float inv = 1.0f / psum;

    float outq[16];
    #pragma unroll
    for (int q = 0; q < 16; ++q) outq[q] = 0.f;
    for (int e = 0; e < 8; ++e) {
        const float pe = p[e] * inv;
        #pragma unroll
        for (int r = 0; r < 16; ++r) {
            const float ar = y[r] * pe;
            #pragma unroll
            for (int q = 0; q < 16; ++q)
                outq[q] = fmaf(ar, Cs[(e * 16 + r) * 16 + q], outq[q]);
        }
    }
    #pragma unroll
    for (int q = 0; q < 4; ++q) {
        f32x4 v = {outq[q * 4 + 0], outq[q * 4 + 1], outq[q * 4 + 2], outq[q * 4 + 3]};
        *(f32x4*)&mixbuf[(size_t)tok * 16 + q * 4] = v;
    }
}

// ---------------- Kernel 3: main GEMM (m97 structure) + fused LoRA/bias epilogue ----------
// C[m,o] = sum_d xbf[m,d]*wbf[o,d] + b[o] + 2.0 * sum_r mixed[m,r]*B_w[o,r]
// 128x128 tile, BK=32, 4 waves (2x2), mfma_f32_16x16x32_bf16, global_load_lds width=16.
// Raster: XCD-bijective; within an XCD, 32 consecutive blocks share one A-panel (tm) and
// sweep all tn (B-tile L2-resident per step, B total L3-resident).
__global__ __launch_bounds__(256) void gemm_kernel(const unsigned short* __restrict__ xbf,
                                                   const unsigned short* __restrict__ wbf,
                                                   const float* __restrict__ bias,
                                                   const float* __restrict__ Bw,
                                                   const float* __restrict__ mixbuf,
                                                   float* __restrict__ out) {
    __shared__ __align__(16) unsigned short As[128 * 32];  // 8 KiB
    __shared__ __align__(16) unsigned short Bs[128 * 32];  // 8 KiB

    const int bid = blockIdx.x;
    const int xcd = bid & 7;
    const int w = bid >> 3;                 // 0..255 per XCD
    const int tm = (w >> 5) * 8 + xcd;      // 64 M-tiles: 8 epochs x 8 XCDs
    const int tn = w & 31;                  // 32 N-tiles swept within an epoch
    const int m0 = tm * 128, n0 = tn * 128;

    const int tid = threadIdx.x;
    const int wave = tid >> 6, lane = tid & 63;
    const int wr = wave >> 1, wc = wave & 1;  // 2x2 wave grid, 64x64 per wave

    f32x4 acc[4][4];
    const f32x4 fz = {0.f, 0.f, 0.f, 0.f};
    #pragma unroll
    for (int mi = 0; mi < 4; ++mi)
        #pragma unroll
        for (int ni = 0; ni < 4; ++ni) acc[mi][ni] = fz;

    const int tA = lane & 15, kq = lane >> 4;

    for (int k0 = 0; k0 < D_DIM; k0 += 32) {
        #pragma unroll
        for (int i = 0; i < 2; ++i) {
            const int chunk = i * 256 + wave * 64 + lane;
            const int row = chunk >> 2;
            const int c8 = (chunk & 3) << 3;
            const unsigned short* ga = xbf + (size_t)(m0 + row) * D_DIM + k0 + c8;
            const unsigned short* gb = wbf + (size_t)(n0 + row) * D_DIM + k0 + c8;
            __builtin_amdgcn_global_load_lds(
                (const __attribute__((address_space(1))) void*)ga,
                (__attribute__((address_space(3))) void*)(As + (i * 256 + wave * 64) * 8),
                16, 0, 0);
            __builtin_amdgcn_global_load_lds(
                (const __attribute__((address_space(1))) void*)gb,
                (__attribute__((address_space(3))) void*)(Bs + (i * 256 + wave * 64) * 8),
                16, 0, 0);
        }
        __syncthreads();

        bf16x8 a[4], b[4];
        #pragma unroll
        for (int mi = 0; mi < 4; ++mi)
            a[mi] = __builtin_bit_cast(
                bf16x8, *(const u16x8*)&As[(wr * 64 + mi * 16 + tA) * 32 + kq * 8]);
        #pragma unroll
        for (int ni = 0; ni < 4; ++ni)
            b[ni] = __builtin_bit_cast(
                bf16x8, *(const u16x8*)&Bs[(wc * 64 + ni * 16 + tA) * 32 + kq * 8]);
        #pragma unroll
        for (int mi = 0; mi < 4; ++mi)
            #pragma unroll
            for (int ni = 0; ni < 4; ++ni)
                acc[mi][ni] =
                    __builtin_amdgcn_mfma_f32_16x16x32_bf16(a[mi], b[ni], acc[mi][ni], 0, 0, 0);
        __syncthreads();
    }

    // epilogue: C/D layout col=lane&15, row=(lane>>4)*4+j
    const int colq = lane & 15, rq = lane >> 4;
    f32x4 bwv[4][4];
    float bcol[4];
    #pragma unroll
    for (int ni = 0; ni < 4; ++ni) {
        const int col = n0 + wc * 64 + ni * 16 + colq;
        bcol[ni] = bias[col];
        #pragma unroll
        for (int k = 0; k < 4; ++k) bwv[ni][k] = *(const f32x4*)&Bw[(size_t)col * 16 + k * 4];
    }
    #pragma unroll
    for (int mi = 0; mi < 4; ++mi) {
        #pragma unroll
        for (int j = 0; j < 4; ++j) {
            const int row = m0 + wr * 64 + mi * 16 + rq * 4 + j;
            const f32x4* mx = (const f32x4*)&mixbuf[(size_t)row * 16];
            const f32x4 m0v = mx[0], m1v = mx[1], m2v = mx[2], m3v = mx[3];
            #pragma unroll
            for (int ni = 0; ni < 4; ++ni) {
                const int col = n0 + wc * 64 + ni * 16 + colq;
                const float lora = dot4(m0v, bwv[ni][0]) + dot4(m1v, bwv[ni][1]) +
                                   dot4(m2v, bwv[ni][2]) + dot4(m3v, bwv[ni][3]);
                out[(size_t)row * O_DIM + col] = acc[mi][ni][j] + bcol[ni] + SCALE_F * lora;
            }
        }
    }
}

extern "C" void kernel_launch(void* const* d_in, const int* in_sizes, int n_in,
                              void* d_out, int out_size, void* d_ws, size_t ws_size,
                              hipStream_t stream) {
    const float* x        = (const float*)d_in[0];
    const float* W_base   = (const float*)d_in[1];
    const float* b_base   = (const float*)d_in[2];
    const float* A_w      = (const float*)d_in[3];
    const float* B_w      = (const float*)d_in[4];
    const float* router_w = (const float*)d_in[5];
    const float* cores    = (const float*)d_in[6];
    float* out = (float*)d_out;

    char* ws = (char*)d_ws;
    unsigned short* xbf = (unsigned short*)ws;                                   // 64 MiB
    unsigned short* wbf = (unsigned short*)(ws + (size_t)M_DIM * D_DIM * 2);     // 32 MiB
    char* after_w = ws + (size_t)M_DIM * D_DIM * 2 + (size_t)O_DIM * D_DIM * 2;
    float* mixbuf = (float*)after_w;                                             // 512 KiB
    float* ypart  = (float*)(after_w + (size_t)M_DIM * 16 * 4);                  // 6 MiB

    convert_bf16_kernel<<<2048, 256, 0, stream>>>(x, xbf, (M_DIM * D_DIM) / 4);
    convert_bf16_kernel<<<2048, 256, 0, stream>>>(W_base, wbf, (O_DIM * D_DIM) / 4);
    partial_mixed_kernel<<<dim3(256, 8), 256, 0, stream>>>(x, A_w, router_w, ypart);
    finalize_mixed_kernel<<<64, 128, 0, stream>>>(ypart, cores, mixbuf);
    gemm_kernel<<<2048, 256, 0, stream>>>(xbf, wbf, b_base, B_w, mixbuf, out);
}

// Round 3
// 339.584 us; speedup vs baseline: 2.7761x; 1.7629x over previous
//
#include <hip/hip_runtime.h>
#include <stdint.h>

#define D_DIM 4096
#define O_DIM 4096
#define M_DIM 8192
#define SCALE_F 2.0f
#define BK 32
#define NKT 128  // D_DIM / BK

typedef __attribute__((ext_vector_type(4))) float f32x4;
typedef __attribute__((ext_vector_type(8))) __bf16 bf16x8;
typedef __attribute__((ext_vector_type(8))) unsigned short u16x8;

__device__ __forceinline__ unsigned short f32_to_bf16_bits(float f) {
    union { float f; uint32_t u; } v; v.f = f;
    return (unsigned short)((v.u + 0x7FFFu + ((v.u >> 16) & 1u)) >> 16);
}

__device__ __forceinline__ float dot4(f32x4 a, f32x4 b) {
    return fmaf(a.x, b.x, fmaf(a.y, b.y, fmaf(a.z, b.z, a.w * b.w)));
}

// swizzle involution on byte offsets within a 16 KiB [256 rows][64 B] tile:
// XOR bits 4-6 with bits 7-9. Keeps 16B chunks intact; spreads the 16-lane
// row-group ds_read_b128 pattern to ~2-way bank aliasing (free).
__device__ __forceinline__ int swz(int b) { return b ^ (((b >> 7) & 7) << 4); }

// ---------------- Kernel 1: f32 -> bf16 convert (W_base) ----------------
__global__ __launch_bounds__(256) void convert_bf16_kernel(const float* __restrict__ src,
                                                           unsigned short* __restrict__ dst,
                                                           int n4) {
    int stride = gridDim.x * blockDim.x;
    for (int i = blockIdx.x * blockDim.x + threadIdx.x; i < n4; i += stride) {
        f32x4 v = ((const f32x4*)src)[i];
        ushort4 o;
        o.x = f32_to_bf16_bits(v.x);
        o.y = f32_to_bf16_bits(v.y);
        o.z = f32_to_bf16_bits(v.z);
        o.w = f32_to_bf16_bits(v.w);
        ((ushort4*)dst)[i] = o;
    }
}

// ---------------- Kernel 2a: partial Y + fused x->bf16 convert ----------------
// grid (256 token-tiles, 8 D-splits), 256 threads. Each block owns the disjoint
// slab x[t0..t0+31, d0..d0+511]: converts it to xbf AND computes partial Y[32,24].
__global__ __launch_bounds__(256) void partial_mixed_kernel(const float* __restrict__ x,
                                                            const float* __restrict__ A_w,
                                                            const float* __restrict__ router_w,
                                                            unsigned short* __restrict__ xbf,
                                                            float* __restrict__ ypart) {
    __shared__ __align__(16) float Xc[32][132];
    __shared__ __align__(16) float Wc[24][132];

    const int tid = threadIdx.x;
    const int t0 = blockIdx.x * 32;
    const int d0 = blockIdx.y * 512;

    const int tg = tid >> 3;
    const int og = tid & 7;
    float acc0 = 0.f, acc1 = 0.f, acc2 = 0.f;

    for (int sub = 0; sub < 4; ++sub) {
        const int dbase = d0 + sub * 128;
        __syncthreads();
        #pragma unroll
        for (int i = 0; i < 4; ++i) {
            int idx = i * 256 + tid;
            int t = idx >> 5, dq = idx & 31;
            f32x4 v = *(const f32x4*)&x[(size_t)(t0 + t) * D_DIM + dbase + dq * 4];
            *(f32x4*)&Xc[t][dq * 4] = v;
            ushort4 o;
            o.x = f32_to_bf16_bits(v.x);
            o.y = f32_to_bf16_bits(v.y);
            o.z = f32_to_bf16_bits(v.z);
            o.w = f32_to_bf16_bits(v.w);
            *(ushort4*)&xbf[(size_t)(t0 + t) * D_DIM + dbase + dq * 4] = o;
        }
        #pragma unroll
        for (int i = 0; i < 3; ++i) {
            int idx = i * 256 + tid;
            int r = idx >> 5, dq = idx & 31;
            const float* src = (r < 16) ? (A_w + (size_t)r * D_DIM)
                                        : (router_w + (size_t)(r - 16) * D_DIM);
            *(f32x4*)&Wc[r][dq * 4] = *(const f32x4*)&src[dbase + dq * 4];
        }
        __syncthreads();
        #pragma unroll
        for (int dq = 0; dq < 32; ++dq) {
            f32x4 xv = *(const f32x4*)&Xc[tg][dq * 4];
            acc0 += dot4(xv, *(const f32x4*)&Wc[og * 3 + 0][dq * 4]);
            acc1 += dot4(xv, *(const f32x4*)&Wc[og * 3 + 1][dq * 4]);
            acc2 += dot4(xv, *(const f32x4*)&Wc[og * 3 + 2][dq * 4]);
        }
    }
    float* dst = ypart + (((size_t)blockIdx.y * 256 + blockIdx.x) * 32 + tg) * 24 + og * 3;
    dst[0] = acc0; dst[1] = acc1; dst[2] = acc2;
}

// ---------------- Kernel 2b: finalize — reduce partials, softmax, expert-core mix -------
__global__ __launch_bounds__(128) void finalize_mixed_kernel(const float* __restrict__ ypart,
                                                             const float* __restrict__ cores,
                                                             float* __restrict__ mixbuf) {
    __shared__ __align__(16) float Cs[2048];
    const int tid = threadIdx.x;
    #pragma unroll
    for (int i = 0; i < 4; ++i) {
        int idx = i * 128 + tid;
        ((f32x4*)Cs)[idx] = ((const f32x4*)cores)[idx];
    }
    __syncthreads();

    const int tok = blockIdx.x * 128 + tid;
    const int tile = tok >> 5, t = tok & 31;

    float y[24];
    #pragma unroll
    for (int j = 0; j < 24; ++j) y[j] = 0.f;
    for (int ds = 0; ds < 8; ++ds) {
        const float* src = ypart + (((size_t)ds * 256 + tile) * 32 + t) * 24;
        #pragma unroll
        for (int j = 0; j < 24; ++j) y[j] += src[j];
    }

    float mx = y[16];
    #pragma unroll
    for (int e = 1; e < 8; ++e) mx = fmaxf(mx, y[16 + e]);
    float p[8], psum = 0.f;
    #pragma unroll
    for (int e = 0; e < 8; ++e) { p[e] = __expf(y[16 + e] - mx); psum += p[e]; }
    const float inv = 1.0f / psum;

    float outq[16];
    #pragma unroll
    for (int q = 0; q < 16; ++q) outq[q] = 0.f;
    for (int e = 0; e < 8; ++e) {
        const float pe = p[e] * inv;
        #pragma unroll
        for (int r = 0; r < 16; ++r) {
            const float ar = y[r] * pe;
            #pragma unroll
            for (int q = 0; q < 16; ++q)
                outq[q] = fmaf(ar, Cs[(e * 16 + r) * 16 + q], outq[q]);
        }
    }
    #pragma unroll
    for (int q = 0; q < 4; ++q) {
        f32x4 v = {outq[q * 4 + 0], outq[q * 4 + 1], outq[q * 4 + 2], outq[q * 4 + 3]};
        *(f32x4*)&mixbuf[(size_t)tok * 16 + q * 4] = v;
    }
}

// ---------------- Kernel 3: 256x256-tile deep-pipelined GEMM + fused epilogue -----------
// 512 threads = 8 waves (2M x 4N), per-wave 128x64 C. BK=32, ring-4 LDS K-tile buffers
// (race-free: iteration j stages K-tile j+3 into the buffer freed at iteration j-1).
// Counted vmcnt(8) once per K-tile; raw s_barrier (no vmcnt drain); T2 swizzle; setprio.
__global__ __launch_bounds__(512, 2) void gemm_kernel(const unsigned short* __restrict__ xbf,
                                                      const unsigned short* __restrict__ wbf,
                                                      const float* __restrict__ bias,
                                                      const float* __restrict__ Bw,
                                                      const float* __restrict__ mixbuf,
                                                      float* __restrict__ out) {
    __shared__ __align__(16) unsigned short lds[4][2][256 * 32];  // 128 KiB

    // raster: bijective XCD swizzle; per-XCD, 16 consecutive blocks share an A-panel.
    const int bid = blockIdx.x;
    const int xcd = bid & 7;
    const int lid = bid >> 3;                 // 0..63
    const int tm = (lid >> 4) * 8 + xcd;      // 0..31
    const int tn = lid & 15;                  // 0..15
    const int m0 = tm * 256, n0 = tn * 256;

    const int tid = threadIdx.x;
    const int wave = tid >> 6, lane = tid & 63;
    const int wr = wave >> 2, wcn = wave & 3;  // 2x4 wave grid

    // ---- per-thread staging source offsets (inverse-swizzled global source) ----
    // unit u in {0,1}: A chunks c = u*512 + tid ; B likewise. LDS dest is linear.
    int aoff[2], boff[2];
    #pragma unroll
    for (int u = 0; u < 2; ++u) {
        int c = u * 512 + tid;
        int g = swz(c * 16);
        int grow = g >> 6, gc8 = (g >> 4) & 3;
        aoff[u] = (m0 + grow) * D_DIM + gc8 * 8;
        boff[u] = (n0 + grow) * D_DIM + gc8 * 8;
    }

    // ---- per-thread swizzled LDS read byte-offsets ----
    const int tA = lane & 15, kq = lane >> 4;
    int aRd[8], bRd[4];
    #pragma unroll
    for (int mi = 0; mi < 8; ++mi)
        aRd[mi] = swz((wr * 128 + mi * 16 + tA) * 64 + kq * 16);
    #pragma unroll
    for (int ni = 0; ni < 4; ++ni)
        bRd[ni] = swz((wcn * 64 + ni * 16 + tA) * 64 + kq * 16);

    f32x4 acc[8][4];
    const f32x4 fz = {0.f, 0.f, 0.f, 0.f};
    #pragma unroll
    for (int mi = 0; mi < 8; ++mi)
        #pragma unroll
        for (int ni = 0; ni < 4; ++ni) acc[mi][ni] = fz;

#define STAGE_UNIT(sb, kt, u, isA)                                                        \
    do {                                                                                  \
        const unsigned short* gsrc =                                                      \
            (isA) ? (xbf + aoff[u] + (kt)*BK) : (wbf + boff[u] + (kt)*BK);                \
        __builtin_amdgcn_global_load_lds(                                                 \
            (const __attribute__((address_space(1))) void*)gsrc,                          \
            (__attribute__((address_space(3))) void*)(&lds[sb][(isA) ? 0 : 1]             \
                                                         [((u)*512 + wave * 64) * 8]),    \
            16, 0, 0);                                                                    \
    } while (0)

    // ---- prologue: stage K-tiles 0..2 (12 gload_lds/thread), wait all but K1,K2 ----
    #pragma unroll
    for (int kt = 0; kt < 3; ++kt) {
        STAGE_UNIT(kt, kt, 0, 1);
        STAGE_UNIT(kt, kt, 1, 1);
        STAGE_UNIT(kt, kt, 0, 0);
        STAGE_UNIT(kt, kt, 1, 0);
    }
    asm volatile("s_waitcnt vmcnt(8)" ::: "memory");
    __builtin_amdgcn_s_barrier();
    asm volatile("" ::: "memory");

    // ---- main loop: 128 K-tiles, 2 phases each ----
    for (int jj = 0; jj < 32; ++jj) {
        #pragma unroll
        for (int i = 0; i < 4; ++i) {
            const int j = jj * 4 + i;
            const int buf = i;             // j & 3
            const int kt = j + 3;
            const int sbuf = (i + 3) & 3;  // kt & 3
            const char* Ab = (const char*)&lds[buf][0][0];
            const char* Bb = (const char*)&lds[buf][1][0];

            // ---- phase 0: read A m0-3 + all B; stage A units of kt; MFMA m0-3 ----
            bf16x8 b0 = __builtin_bit_cast(bf16x8, *(const u16x8*)(Bb + bRd[0]));
            bf16x8 b1 = __builtin_bit_cast(bf16x8, *(const u16x8*)(Bb + bRd[1]));
            bf16x8 b2 = __builtin_bit_cast(bf16x8, *(const u16x8*)(Bb + bRd[2]));
            bf16x8 b3 = __builtin_bit_cast(bf16x8, *(const u16x8*)(Bb + bRd[3]));
            bf16x8 a0 = __builtin_bit_cast(bf16x8, *(const u16x8*)(Ab + aRd[0]));
            bf16x8 a1 = __builtin_bit_cast(bf16x8, *(const u16x8*)(Ab + aRd[1]));
            bf16x8 a2 = __builtin_bit_cast(bf16x8, *(const u16x8*)(Ab + aRd[2]));
            bf16x8 a3 = __builtin_bit_cast(bf16x8, *(const u16x8*)(Ab + aRd[3]));
            if (kt < NKT) {
                STAGE_UNIT(sbuf, kt, 0, 1);
                STAGE_UNIT(sbuf, kt, 1, 1);
            }
            asm volatile("" ::: "memory");
            __builtin_amdgcn_s_barrier();
            asm volatile("s_waitcnt lgkmcnt(0)" ::: "memory");
            __builtin_amdgcn_s_setprio(1);
            acc[0][0] = __builtin_amdgcn_mfma_f32_16x16x32_bf16(a0, b0, acc[0][0], 0, 0, 0);
            acc[0][1] = __builtin_amdgcn_mfma_f32_16x16x32_bf16(a0, b1, acc[0][1], 0, 0, 0);
            acc[0][2] = __builtin_amdgcn_mfma_f32_16x16x32_bf16(a0, b2, acc[0][2], 0, 0, 0);
            acc[0][3] = __builtin_amdgcn_mfma_f32_16x16x32_bf16(a0, b3, acc[0][3], 0, 0, 0);
            acc[1][0] = __builtin_amdgcn_mfma_f32_16x16x32_bf16(a1, b0, acc[1][0], 0, 0, 0);
            acc[1][1] = __builtin_amdgcn_mfma_f32_16x16x32_bf16(a1, b1, acc[1][1], 0, 0, 0);
            acc[1][2] = __builtin_amdgcn_mfma_f32_16x16x32_bf16(a1, b2, acc[1][2], 0, 0, 0);
            acc[1][3] = __builtin_amdgcn_mfma_f32_16x16x32_bf16(a1, b3, acc[1][3], 0, 0, 0);
            acc[2][0] = __builtin_amdgcn_mfma_f32_16x16x32_bf16(a2, b0, acc[2][0], 0, 0, 0);
            acc[2][1] = __builtin_amdgcn_mfma_f32_16x16x32_bf16(a2, b1, acc[2][1], 0, 0, 0);
            acc[2][2] = __builtin_amdgcn_mfma_f32_16x16x32_bf16(a2, b2, acc[2][2], 0, 0, 0);
            acc[2][3] = __builtin_amdgcn_mfma_f32_16x16x32_bf16(a2, b3, acc[2][3], 0, 0, 0);
            acc[3][0] = __builtin_amdgcn_mfma_f32_16x16x32_bf16(a3, b0, acc[3][0], 0, 0, 0);
            acc[3][1] = __builtin_amdgcn_mfma_f32_16x16x32_bf16(a3, b1, acc[3][1], 0, 0, 0);
            acc[3][2] = __builtin_amdgcn_mfma_f32_16x16x32_bf16(a3, b2, acc[3][2], 0, 0, 0);
            acc[3][3] = __builtin_amdgcn_mfma_f32_16x16x32_bf16(a3, b3, acc[3][3], 0, 0, 0);
            __builtin_amdgcn_s_setprio(0);
            asm volatile("" ::: "memory");
            __builtin_amdgcn_s_barrier();
            asm volatile("" ::: "memory");

            // ---- phase 1: read A m4-7; stage B units of kt; vmcnt(8); MFMA m4-7 ----
            bf16x8 a4 = __builtin_bit_cast(bf16x8, *(const u16x8*)(Ab + aRd[4]));
            bf16x8 a5 = __builtin_bit_cast(bf16x8, *(const u16x8*)(Ab + aRd[5]));
            bf16x8 a6 = __builtin_bit_cast(bf16x8, *(const u16x8*)(Ab + aRd[6]));
            bf16x8 a7 = __builtin_bit_cast(bf16x8, *(const u16x8*)(Ab + aRd[7]));
            if (kt < NKT) {
                STAGE_UNIT(sbuf, kt, 0, 0);
                STAGE_UNIT(sbuf, kt, 1, 0);
            }
            asm volatile("s_waitcnt vmcnt(8)" ::: "memory");
            __builtin_amdgcn_s_barrier();
            asm volatile("s_waitcnt lgkmcnt(0)" ::: "memory");
            __builtin_amdgcn_s_setprio(1);
            acc[4][0] = __builtin_amdgcn_mfma_f32_16x16x32_bf16(a4, b0, acc[4][0], 0, 0, 0);
            acc[4][1] = __builtin_amdgcn_mfma_f32_16x16x32_bf16(a4, b1, acc[4][1], 0, 0, 0);
            acc[4][2] = __builtin_amdgcn_mfma_f32_16x16x32_bf16(a4, b2, acc[4][2], 0, 0, 0);
            acc[4][3] = __builtin_amdgcn_mfma_f32_16x16x32_bf16(a4, b3, acc[4][3], 0, 0, 0);
            acc[5][0] = __builtin_amdgcn_mfma_f32_16x16x32_bf16(a5, b0, acc[5][0], 0, 0, 0);
            acc[5][1] = __builtin_amdgcn_mfma_f32_16x16x32_bf16(a5, b1, acc[5][1], 0, 0, 0);
            acc[5][2] = __builtin_amdgcn_mfma_f32_16x16x32_bf16(a5, b2, acc[5][2], 0, 0, 0);
            acc[5][3] = __builtin_amdgcn_mfma_f32_16x16x32_bf16(a5, b3, acc[5][3], 0, 0, 0);
            acc[6][0] = __builtin_amdgcn_mfma_f32_16x16x32_bf16(a6, b0, acc[6][0], 0, 0, 0);
            acc[6][1] = __builtin_amdgcn_mfma_f32_16x16x32_bf16(a6, b1, acc[6][1], 0, 0, 0);
            acc[6][2] = __builtin_amdgcn_mfma_f32_16x16x32_bf16(a6, b2, acc[6][2], 0, 0, 0);
            acc[6][3] = __builtin_amdgcn_mfma_f32_16x16x32_bf16(a6, b3, acc[6][3], 0, 0, 0);
            acc[7][0] = __builtin_amdgcn_mfma_f32_16x16x32_bf16(a7, b0, acc[7][0], 0, 0, 0);
            acc[7][1] = __builtin_amdgcn_mfma_f32_16x16x32_bf16(a7, b1, acc[7][1], 0, 0, 0);
            acc[7][2] = __builtin_amdgcn_mfma_f32_16x16x32_bf16(a7, b2, acc[7][2], 0, 0, 0);
            acc[7][3] = __builtin_amdgcn_mfma_f32_16x16x32_bf16(a7, b3, acc[7][3], 0, 0, 0);
            __builtin_amdgcn_s_setprio(0);
            asm volatile("" ::: "memory");
            __builtin_amdgcn_s_barrier();
            asm volatile("" ::: "memory");
        }
    }
#undef STAGE_UNIT

    // ---- epilogue: C/D layout col=lane&15, row=(lane>>4)*4+j ----
    const int colq = lane & 15, rq = lane >> 4;
    f32x4 bwv[4][4];
    float bcol[4];
    #pragma unroll
    for (int ni = 0; ni < 4; ++ni) {
        const int col = n0 + wcn * 64 + ni * 16 + colq;
        bcol[ni] = bias[col];
        #pragma unroll
        for (int k = 0; k < 4; ++k) bwv[ni][k] = *(const f32x4*)&Bw[(size_t)col * 16 + k * 4];
    }
    #pragma unroll
    for (int mi = 0; mi < 8; ++mi) {
        #pragma unroll
        for (int j = 0; j < 4; ++j) {
            const int row = m0 + wr * 128 + mi * 16 + rq * 4 + j;
            const f32x4* mx = (const f32x4*)&mixbuf[(size_t)row * 16];
            const f32x4 m0v = mx[0], m1v = mx[1], m2v = mx[2], m3v = mx[3];
            #pragma unroll
            for (int ni = 0; ni < 4; ++ni) {
                const int col = n0 + wcn * 64 + ni * 16 + colq;
                const float lora = dot4(m0v, bwv[ni][0]) + dot4(m1v, bwv[ni][1]) +
                                   dot4(m2v, bwv[ni][2]) + dot4(m3v, bwv[ni][3]);
                out[(size_t)row * O_DIM + col] = acc[mi][ni][j] + bcol[ni] + SCALE_F * lora;
            }
        }
    }
}

extern "C" void kernel_launch(void* const* d_in, const int* in_sizes, int n_in,
                              void* d_out, int out_size, void* d_ws, size_t ws_size,
                              hipStream_t stream) {
    const float* x        = (const float*)d_in[0];
    const float* W_base   = (const float*)d_in[1];
    const float* b_base   = (const float*)d_in[2];
    const float* A_w      = (const float*)d_in[3];
    const float* B_w      = (const float*)d_in[4];
    const float* router_w = (const float*)d_in[5];
    const float* cores    = (const float*)d_in[6];
    float* out = (float*)d_out;

    char* ws = (char*)d_ws;
    unsigned short* xbf = (unsigned short*)ws;                                   // 64 MiB
    unsigned short* wbf = (unsigned short*)(ws + (size_t)M_DIM * D_DIM * 2);     // 32 MiB
    char* after_w = ws + (size_t)M_DIM * D_DIM * 2 + (size_t)O_DIM * D_DIM * 2;
    float* mixbuf = (float*)after_w;                                             // 512 KiB
    float* ypart  = (float*)(after_w + (size_t)M_DIM * 16 * 4);                  // 6 MiB

    convert_bf16_kernel<<<2048, 256, 0, stream>>>(W_base, wbf, (O_DIM * D_DIM) / 4);
    partial_mixed_kernel<<<dim3(256, 8), 256, 0, stream>>>(x, A_w, router_w, xbf, ypart);
    finalize_mixed_kernel<<<64, 128, 0, stream>>>(ypart, cores, mixbuf);
    gemm_kernel<<<512, 512, 0, stream>>>(xbf, wbf, b_base, B_w, mixbuf, out);
}